// Round 11
// baseline (38.269 us; speedup 1.0000x reference)
//
#include <hip/hip_runtime.h>
#include <math.h>

#define JN 9
#define BLK 128   // wave 0 = producer (A), wave 1 = consumer (B)
#define CH 64     // chains per block

__device__ __forceinline__ void mat3_vec(const float* R, const float* x, float* y) {
    y[0] = R[0]*x[0] + R[1]*x[1] + R[2]*x[2];
    y[1] = R[3]*x[0] + R[4]*x[1] + R[5]*x[2];
    y[2] = R[6]*x[0] + R[7]*x[1] + R[8]*x[2];
}
__device__ __forceinline__ void mat3T_vec(const float* R, const float* x, float* y) {
    y[0] = R[0]*x[0] + R[3]*x[1] + R[6]*x[2];
    y[1] = R[1]*x[0] + R[4]*x[1] + R[7]*x[2];
    y[2] = R[2]*x[0] + R[5]*x[1] + R[8]*x[2];
}
__device__ __forceinline__ void cross3(const float* a, const float* b, float* o) {
    o[0] = a[1]*b[2] - a[2]*b[1];
    o[1] = a[2]*b[0] - a[0]*b[2];
    o[2] = a[0]*b[1] - a[1]*b[0];
}
// y = Adjoint(T) x, T=(R,p): y_w = R x_w ; y_v = p x (R x_w) + R x_v
__device__ __forceinline__ void adj_apply(const float* R, const float* p,
                                          const float* x, float* y) {
    float t[3], cr[3], rv[3];
    mat3_vec(R, x, t);
    cross3(p, t, cr);
    mat3_vec(R, x + 3, rv);
    y[0] = t[0]; y[1] = t[1]; y[2] = t[2];
    y[3] = cr[0] + rv[0]; y[4] = cr[1] + rv[1]; y[5] = cr[2] + rv[2];
}
// y = Adjoint(T)^T x: y_w = R^T (x_w - p x x_v) ; y_v = R^T x_v
__device__ __forceinline__ void adjT_apply(const float* R, const float* p,
                                           const float* x, float* y) {
    float cr[3], t[3];
    cross3(p, x + 3, cr);
    t[0] = x[0] - cr[0]; t[1] = x[1] - cr[1]; t[2] = x[2] - cr[2];
    mat3T_vec(R, t, y);
    mat3T_vec(R, x + 3, y + 3);
}

// exp6(-Aj q) @ inv(M_j)  -> TR, Tp    (R5 verified body)
__device__ __forceinline__ void make_T(const float* Aj, const float* Mj, float qj,
                                       float* TR, float* Tp)
{
    const float w0 = -Aj[0]*qj, w1 = -Aj[1]*qj, w2 = -Aj[2]*qj;
    const float l0 = -Aj[3]*qj, l1 = -Aj[4]*qj, l2 = -Aj[5]*qj;
    const float th = sqrtf(w0*w0 + w1*w1 + w2*w2);
    const bool near = th < 1e-6f;
    const float safe = near ? 1.f : th;
    const float inv = __builtin_amdgcn_rcpf(safe);
    const float x = w0*inv, y = w1*inv, z = w2*inv;
    const float st = __sinf(th), ct = __cosf(th);
    const float s2 = 1.f - ct;
    const float a00 = -(z*z+y*y), a11 = -(z*z+x*x), a22 = -(y*y+x*x);
    const float a01 = x*y, a02 = x*z, a12 = y*z;
    float R[9];
    R[0]=1.f+s2*a00;   R[1]=-st*z+s2*a01; R[2]= st*y+s2*a02;
    R[3]= st*z+s2*a01; R[4]=1.f+s2*a11;   R[5]=-st*x+s2*a12;
    R[6]=-st*y+s2*a02; R[7]= st*x+s2*a12; R[8]=1.f+s2*a22;
    if (near) { R[0]=1;R[1]=0;R[2]=0;R[3]=0;R[4]=1;R[5]=0;R[6]=0;R[7]=0;R[8]=1; }
    const float g3 = th - st;
    const float u0 = l0*inv, u1 = l1*inv, u2 = l2*inv;
    float p0 = th*u0 + s2*(-z*u1+y*u2) + g3*(a00*u0+a01*u1+a02*u2);
    float p1 = th*u1 + s2*( z*u0-x*u2) + g3*(a01*u0+a11*u1+a12*u2);
    float p2 = th*u2 + s2*(-y*u0+x*u1) + g3*(a02*u0+a12*u1+a22*u2);
    if (near) { p0=l0; p1=l1; p2=l2; }
#pragma unroll
    for (int r = 0; r < 3; ++r)
#pragma unroll
        for (int cc = 0; cc < 3; ++cc)
            TR[r*3+cc] = R[r*3+0]*Mj[cc*4+0] + R[r*3+1]*Mj[cc*4+1] + R[r*3+2]*Mj[cc*4+2];
    const float mp0 = Mj[3], mp1 = Mj[7], mp2 = Mj[11];
    Tp[0] = p0 - (TR[0]*mp0 + TR[1]*mp1 + TR[2]*mp2);
    Tp[1] = p1 - (TR[3]*mp0 + TR[4]*mp1 + TR[5]*mp2);
    Tp[2] = p2 - (TR[6]*mp0 + TR[7]*mp1 + TR[8]*mp2);
}

// ---------- producer/consumer split: 2 waves cooperate on 64 chains ----------
__global__ void __launch_bounds__(BLK, 4)
id_pc(const float* __restrict__ q, const float* __restrict__ dq,
      const float* __restrict__ ddq, const float* __restrict__ gvec,
      const float* __restrict__ Ftip, const float* __restrict__ Alist,
      const float* __restrict__ Mlist, const float* __restrict__ Glist,
      float* __restrict__ out, int B)
{
    __shared__ float ringT[3][12][CH];     // A -> B : T_j (TR 0-8, Tp 9-11)
    __shared__ float ringW[2][6][CH];      // B -> A : W_j
    __shared__ float sBsig[JN*6 + JN][CH]; // A only : B_0..B_8 then sigma_0..8

    const int lane = threadIdx.x & 63;
    const int wid  = threadIdx.x >> 6;
    const int c = blockIdx.x * CH + lane;

    // A state
    float XR[9]  = {1,0,0, 0,1,0, 0,0,1};   // X_{j-1} during iter j (pre-update)
    float Xp[3]  = {0,0,0};
    float XRp[9] = {1,0,0, 0,1,0, 0,0,1};   // X_{j-2} during iter j
    float Xpp[3] = {0,0,0};
    float U[6]   = {0,0,0,0,0,0};
    float Bprev[6] = {0,0,0,0,0,0};
    float Ft[6];
    // B state (reference link-frame recursion)
    float vl[6] = {0,0,0,0,0,0};
    float al[6] = {0,0,0,0,0,0};

    if (wid == 0) {
#pragma unroll
        for (int k = 0; k < 6; ++k) Ft[k] = Ftip[(size_t)c*6 + k];
    } else {
        al[3] = -gvec[0]; al[4] = -gvec[1]; al[5] = -gvec[2];
    }

#pragma unroll 1
    for (int j = 0; j <= JN + 1; ++j) {     // 11 iterations
        if (wid == 0) {
            // ---- S_{j-2} = Ad(X_{j-2})^T W_{j-2} ; U += S ----
            if (j >= 2) {
                float W[6], S[6];
#pragma unroll
                for (int k = 0; k < 6; ++k) W[k] = ringW[(j-2) & 1][k][lane];
                adjT_apply(XRp, Xpp, W, S);
#pragma unroll
                for (int k = 0; k < 6; ++k) U[k] += S[k];
            }
            // ---- sigma_{j-1} = B_{j-1} . U_{j-2} ----
            if (j >= 1 && j <= JN) {
                float sg = Bprev[0]*U[0]+Bprev[1]*U[1]+Bprev[2]*U[2]
                         + Bprev[3]*U[3]+Bprev[4]*U[4]+Bprev[5]*U[5];
                sBsig[JN*6 + (j-1)][lane] = sg;
            }
            // ---- shift X history: XRp <- X_{j-1} ----
#pragma unroll
            for (int e = 0; e < 9; ++e) XRp[e] = XR[e];
            Xpp[0]=Xp[0]; Xpp[1]=Xp[1]; Xpp[2]=Xp[2];

            if (j < JN) {
                const float* Am = Alist + j*6;
                const float* Mj = Mlist + j*16;
                float Aj[6];
#pragma unroll
                for (int k = 0; k < 6; ++k) Aj[k] = Am[k];
                const float qj = q[(size_t)c*JN + j];
                float TR[9], Tp[3];
                make_T(Aj, Mj, qj, TR, Tp);
                // publish T_j
#pragma unroll
                for (int e = 0; e < 9; ++e) ringT[j%3][e][lane] = TR[e];
                ringT[j%3][9][lane]  = Tp[0];
                ringT[j%3][10][lane] = Tp[1];
                ringT[j%3][11][lane] = Tp[2];
                // X_j = T_j @ X_{j-1}
                {
                    float nR[9], np[3];
#pragma unroll
                    for (int r = 0; r < 3; ++r)
#pragma unroll
                        for (int cc = 0; cc < 3; ++cc)
                            nR[r*3+cc] = TR[r*3+0]*XR[0*3+cc] + TR[r*3+1]*XR[1*3+cc] + TR[r*3+2]*XR[2*3+cc];
                    mat3_vec(TR, Xp, np);
#pragma unroll
                    for (int e = 0; e < 9; ++e) XR[e] = nR[e];
                    Xp[0] = np[0]+Tp[0]; Xp[1] = np[1]+Tp[1]; Xp[2] = np[2]+Tp[2];
                }
                // B_j = Ad(X_j^{-1}) A_j
                float Bv[6];
                {
                    float ip[3], tw[3], tv[3], cr[3];
                    mat3T_vec(XR, Xp, ip);
                    ip[0]=-ip[0]; ip[1]=-ip[1]; ip[2]=-ip[2];
                    mat3T_vec(XR, Aj, tw);
                    mat3T_vec(XR, Aj+3, tv);
                    cross3(ip, tw, cr);
                    Bv[0]=tw[0]; Bv[1]=tw[1]; Bv[2]=tw[2];
                    Bv[3]=cr[0]+tv[0]; Bv[4]=cr[1]+tv[1]; Bv[5]=cr[2]+tv[2];
                }
#pragma unroll
                for (int k = 0; k < 6; ++k) { sBsig[j*6+k][lane] = Bv[k]; Bprev[k] = Bv[k]; }
            }
        } else {
            // ---- B consumes T_{j-1}: reference v/a recursion + W ----
            if (j >= 1 && j <= JN) {
                const int jj = j - 1;
                const float dqj  = dq[(size_t)c*JN + jj];
                const float ddqj = ddq[(size_t)c*JN + jj];
                float TR[9], Tp[3];
#pragma unroll
                for (int e = 0; e < 9; ++e) TR[e] = ringT[jj%3][e][lane];
                Tp[0] = ringT[jj%3][9][lane];
                Tp[1] = ringT[jj%3][10][lane];
                Tp[2] = ringT[jj%3][11][lane];
                const float* Am = Alist + jj*6;
                float Aj[6];
#pragma unroll
                for (int k = 0; k < 6; ++k) Aj[k] = Am[k];
                // v = Ad(T)v + A dq
                float vn[6];
                adj_apply(TR, Tp, vl, vn);
#pragma unroll
                for (int k = 0; k < 6; ++k) vn[k] += Aj[k]*dqj;
                // a = Ad(T)a + ad(vn)A dq + A ddq
                float an[6];
                adj_apply(TR, Tp, al, an);
                {
                    float t0[3], t1[3], t2[3];
                    cross3(vn, Aj, t0);
                    cross3(vn+3, Aj, t1);
                    cross3(vn, Aj+3, t2);
                    an[0] += t0[0]*dqj + Aj[0]*ddqj;
                    an[1] += t0[1]*dqj + Aj[1]*ddqj;
                    an[2] += t0[2]*dqj + Aj[2]*ddqj;
                    an[3] += (t1[0]+t2[0])*dqj + Aj[3]*ddqj;
                    an[4] += (t1[1]+t2[1])*dqj + Aj[4]*ddqj;
                    an[5] += (t1[2]+t2[2])*dqj + Aj[5]*ddqj;
                }
#pragma unroll
                for (int k = 0; k < 6; ++k) { vl[k] = vn[k]; al[k] = an[k]; }
                // W = G a - ad(v)^T (G v)
                const float* Gm = Glist + jj*36;
                float Gv[6], Ga[6];
#pragma unroll
                for (int r = 0; r < 6; ++r) {
                    float sv = 0.f, sa = 0.f;
#pragma unroll
                    for (int kk = 0; kk < 6; ++kk) { sv += Gm[r*6+kk]*vl[kk]; sa += Gm[r*6+kk]*al[kk]; }
                    Gv[r] = sv; Ga[r] = sa;
                }
                float cw[3], cv[3], cb[3];
                cross3(vl, Gv, cw);
                cross3(vl+3, Gv+3, cv);
                cross3(vl, Gv+3, cb);
                ringW[jj & 1][0][lane] = Ga[0]+cw[0]+cv[0];
                ringW[jj & 1][1][lane] = Ga[1]+cw[1]+cv[1];
                ringW[jj & 1][2][lane] = Ga[2]+cw[2]+cv[2];
                ringW[jj & 1][3][lane] = Ga[3]+cb[0];
                ringW[jj & 1][4][lane] = Ga[4]+cb[1];
                ringW[jj & 1][5][lane] = Ga[5]+cb[2];
            }
        }
        __syncthreads();
    }

    // ---- A-only epilogue: E = U_8 + Ad(X_9)^T Ftip ; tau ----
    if (wid == 0) {
        const float* M9 = Mlist + JN * 16;
        float R9[9], p9[3];
#pragma unroll
        for (int r = 0; r < 3; ++r)
#pragma unroll
            for (int cc = 0; cc < 3; ++cc)
                R9[r*3+cc] = M9[0*4+r]*XR[0*3+cc] + M9[1*4+r]*XR[1*3+cc] + M9[2*4+r]*XR[2*3+cc];
        float t[3] = {Xp[0]-M9[3], Xp[1]-M9[7], Xp[2]-M9[11]};
        p9[0] = M9[0]*t[0] + M9[4]*t[1] + M9[8]*t[2];
        p9[1] = M9[1]*t[0] + M9[5]*t[1] + M9[9]*t[2];
        p9[2] = M9[2]*t[0] + M9[6]*t[1] + M9[10]*t[2];
        float Z[6], E[6];
        adjT_apply(R9, p9, Ft, Z);
#pragma unroll
        for (int k = 0; k < 6; ++k) E[k] = U[k] + Z[k];
#pragma unroll
        for (int i = 0; i < JN; ++i) {
            float d = -sBsig[JN*6 + i][lane];
#pragma unroll
            for (int k = 0; k < 6; ++k) d += sBsig[i*6+k][lane] * E[k];
            out[(size_t)c*JN + i] = d;
        }
    }
}

// ---------- fallback: R5 kernel (best single-wave, 26.9us) for any B ----------
__global__ void __launch_bounds__(BLK)
id_kernel_fb(const float* __restrict__ q, const float* __restrict__ dq,
             const float* __restrict__ ddq, const float* __restrict__ gvec,
             const float* __restrict__ Ftip, const float* __restrict__ Alist,
             const float* __restrict__ Mlist, const float* __restrict__ Glist,
             float* __restrict__ out, int B)
{
    __shared__ float sB[JN * 6][BLK];
    __shared__ float sSig[JN][BLK];
    const int tid = threadIdx.x;
    const int b = blockIdx.x * BLK + tid;
    if (b >= B) return;
    float XR[9] = {1.f,0.f,0.f, 0.f,1.f,0.f, 0.f,0.f,1.f};
    float Xp[3] = {0.f, 0.f, 0.f};
    float bv[6] = {0.f,0.f,0.f,0.f,0.f,0.f};
    float ba[6] = {0.f, 0.f, 0.f, -gvec[0], -gvec[1], -gvec[2]};
    float U[6]  = {0.f,0.f,0.f,0.f,0.f,0.f};
#pragma unroll 1
    for (int j = 0; j < JN; ++j) {
        const float* Am = Alist + j * 6;
        const float* Gm = Glist + j * 36;
        const float* Mj = Mlist + j * 16;
        float Aj[6];
#pragma unroll
        for (int k = 0; k < 6; ++k) Aj[k] = Am[k];
        const float qj = q[b*JN+j], dqj = dq[b*JN+j], ddqj = ddq[b*JN+j];
        float TR[9], Tp[3];
        make_T(Aj, Mj, qj, TR, Tp);
        {
            float nR[9], np[3];
#pragma unroll
            for (int r = 0; r < 3; ++r)
#pragma unroll
                for (int cc = 0; cc < 3; ++cc)
                    nR[r*3+cc] = TR[r*3+0]*XR[0*3+cc] + TR[r*3+1]*XR[1*3+cc] + TR[r*3+2]*XR[2*3+cc];
            mat3_vec(TR, Xp, np);
#pragma unroll
            for (int e = 0; e < 9; ++e) XR[e] = nR[e];
            Xp[0] = np[0]+Tp[0]; Xp[1] = np[1]+Tp[1]; Xp[2] = np[2]+Tp[2];
        }
        float Bv[6];
        {
            float ip[3], tw[3], tvv[3], cr[3];
            mat3T_vec(XR, Xp, ip);
            ip[0]=-ip[0]; ip[1]=-ip[1]; ip[2]=-ip[2];
            mat3T_vec(XR, Aj, tw);
            mat3T_vec(XR, Aj+3, tvv);
            cross3(ip, tw, cr);
            Bv[0]=tw[0]; Bv[1]=tw[1]; Bv[2]=tw[2];
            Bv[3]=cr[0]+tvv[0]; Bv[4]=cr[1]+tvv[1]; Bv[5]=cr[2]+tvv[2];
        }
        float sg = Bv[0]*U[0]+Bv[1]*U[1]+Bv[2]*U[2]+Bv[3]*U[3]+Bv[4]*U[4]+Bv[5]*U[5];
#pragma unroll
        for (int k = 0; k < 6; ++k) bv[k] += Bv[k]*dqj;
        {
            float t0[3], t1[3], t2[3];
            cross3(bv, Bv, t0); cross3(bv+3, Bv, t1); cross3(bv, Bv+3, t2);
            ba[0] += t0[0]*dqj + Bv[0]*ddqj;
            ba[1] += t0[1]*dqj + Bv[1]*ddqj;
            ba[2] += t0[2]*dqj + Bv[2]*ddqj;
            ba[3] += (t1[0]+t2[0])*dqj + Bv[3]*ddqj;
            ba[4] += (t1[1]+t2[1])*dqj + Bv[4]*ddqj;
            ba[5] += (t1[2]+t2[2])*dqj + Bv[5]*ddqj;
        }
        float vl[6], al[6];
        adj_apply(XR, Xp, bv, vl);
        adj_apply(XR, Xp, ba, al);
        float Gv[6], Ga[6];
#pragma unroll
        for (int r = 0; r < 6; ++r) {
            float sv = 0.f, sa = 0.f;
#pragma unroll
            for (int kk = 0; kk < 6; ++kk) { sv += Gm[r*6+kk]*vl[kk]; sa += Gm[r*6+kk]*al[kk]; }
            Gv[r] = sv; Ga[r] = sa;
        }
        float W[6];
        {
            float cw[3], cv[3], cb[3];
            cross3(vl, Gv, cw); cross3(vl+3, Gv+3, cv); cross3(vl, Gv+3, cb);
            W[0]=Ga[0]+cw[0]+cv[0]; W[1]=Ga[1]+cw[1]+cv[1]; W[2]=Ga[2]+cw[2]+cv[2];
            W[3]=Ga[3]+cb[0];       W[4]=Ga[4]+cb[1];       W[5]=Ga[5]+cb[2];
        }
        {
            float S[6];
            adjT_apply(XR, Xp, W, S);
#pragma unroll
            for (int k = 0; k < 6; ++k) U[k] += S[k];
        }
#pragma unroll
        for (int k = 0; k < 6; ++k) sB[j*6+k][tid] = Bv[k];
        sSig[j][tid] = sg;
    }
    float E[6];
    {
        const float* M9 = Mlist + JN * 16;
        float R9[9], p9[3];
#pragma unroll
        for (int r = 0; r < 3; ++r)
#pragma unroll
            for (int cc = 0; cc < 3; ++cc)
                R9[r*3+cc] = M9[0*4+r]*XR[0*3+cc] + M9[1*4+r]*XR[1*3+cc] + M9[2*4+r]*XR[2*3+cc];
        float t[3] = {Xp[0]-M9[3], Xp[1]-M9[7], Xp[2]-M9[11]};
        p9[0] = M9[0]*t[0] + M9[4]*t[1] + M9[8]*t[2];
        p9[1] = M9[1]*t[0] + M9[5]*t[1] + M9[9]*t[2];
        p9[2] = M9[2]*t[0] + M9[6]*t[1] + M9[10]*t[2];
        float Ftl[6];
#pragma unroll
        for (int k = 0; k < 6; ++k) Ftl[k] = Ftip[b*6+k];
        float Z[6];
        adjT_apply(R9, p9, Ftl, Z);
#pragma unroll
        for (int k = 0; k < 6; ++k) E[k] = U[k] + Z[k];
    }
#pragma unroll
    for (int i = 0; i < JN; ++i) {
        float d = -sSig[i][tid];
#pragma unroll
        for (int k = 0; k < 6; ++k) d += sB[i*6+k][tid] * E[k];
        out[b*JN+i] = d;
    }
}

extern "C" void kernel_launch(void* const* d_in, const int* in_sizes, int n_in,
                              void* d_out, int out_size, void* d_ws, size_t ws_size,
                              hipStream_t stream) {
    const float* q     = (const float*)d_in[0];
    const float* dq    = (const float*)d_in[1];
    const float* ddq   = (const float*)d_in[2];
    const float* g     = (const float*)d_in[3];
    const float* Ftip  = (const float*)d_in[4];
    const float* Alist = (const float*)d_in[5];
    const float* Mlist = (const float*)d_in[6];
    const float* Glist = (const float*)d_in[7];
    float* out = (float*)d_out;
    const int B = in_sizes[0] / JN;

    if ((B % CH) == 0) {
        const int grid = B / CH;
        hipLaunchKernelGGL(id_pc, dim3(grid), dim3(BLK), 0, stream,
                           q, dq, ddq, g, Ftip, Alist, Mlist, Glist, out, B);
    } else {
        const int grid = (B + BLK - 1) / BLK;
        hipLaunchKernelGGL(id_kernel_fb, dim3(grid), dim3(BLK), 0, stream,
                           q, dq, ddq, g, Ftip, Alist, Mlist, Glist, out, B);
    }
}

// Round 12
// 28.864 us; speedup vs baseline: 1.3259x; 1.3259x over previous
//
#include <hip/hip_runtime.h>
#include <math.h>

#define JN 9
#define BLK 128

__device__ __forceinline__ void mat3_vec(const float* R, const float* x, float* y) {
    y[0] = R[0]*x[0] + R[1]*x[1] + R[2]*x[2];
    y[1] = R[3]*x[0] + R[4]*x[1] + R[5]*x[2];
    y[2] = R[6]*x[0] + R[7]*x[1] + R[8]*x[2];
}
__device__ __forceinline__ void mat3T_vec(const float* R, const float* x, float* y) {
    y[0] = R[0]*x[0] + R[3]*x[1] + R[6]*x[2];
    y[1] = R[1]*x[0] + R[4]*x[1] + R[7]*x[2];
    y[2] = R[2]*x[0] + R[5]*x[1] + R[8]*x[2];
}
__device__ __forceinline__ void cross3(const float* a, const float* b, float* o) {
    o[0] = a[1]*b[2] - a[2]*b[1];
    o[1] = a[2]*b[0] - a[0]*b[2];
    o[2] = a[0]*b[1] - a[1]*b[0];
}
// y = Adjoint(T) x, T=(R,p): y_w = R x_w ; y_v = p x (R x_w) + R x_v
__device__ __forceinline__ void adj_apply(const float* R, const float* p,
                                          const float* x, float* y) {
    float t[3], cr[3], rv[3];
    mat3_vec(R, x, t);
    cross3(p, t, cr);
    mat3_vec(R, x + 3, rv);
    y[0] = t[0]; y[1] = t[1]; y[2] = t[2];
    y[3] = cr[0] + rv[0]; y[4] = cr[1] + rv[1]; y[5] = cr[2] + rv[2];
}
// y = Adjoint(T)^T x: y_w = R^T (x_w - p x x_v) ; y_v = R^T x_v
__device__ __forceinline__ void adjT_apply(const float* R, const float* p,
                                           const float* x, float* y) {
    float cr[3], t[3];
    cross3(p, x + 3, cr);
    t[0] = x[0] - cr[0]; t[1] = x[1] - cr[1]; t[2] = x[2] - cr[2];
    mat3T_vec(R, t, y);
    mat3T_vec(R, x + 3, y + 3);
}

// exp6(-Aj q) @ inv(M_j)  -> TR, Tp    (R5 verified body)
__device__ __forceinline__ void make_T(const float* __restrict__ Aj,
                                       const float* __restrict__ Mj, float qj,
                                       float* TR, float* Tp)
{
    const float w0 = -Aj[0]*qj, w1 = -Aj[1]*qj, w2 = -Aj[2]*qj;
    const float l0 = -Aj[3]*qj, l1 = -Aj[4]*qj, l2 = -Aj[5]*qj;
    const float th = sqrtf(w0*w0 + w1*w1 + w2*w2);
    const bool near = th < 1e-6f;
    const float safe = near ? 1.f : th;
    const float inv = __builtin_amdgcn_rcpf(safe);
    const float x = w0*inv, y = w1*inv, z = w2*inv;
    const float st = __sinf(th), ct = __cosf(th);
    const float s2 = 1.f - ct;
    const float a00 = -(z*z+y*y), a11 = -(z*z+x*x), a22 = -(y*y+x*x);
    const float a01 = x*y, a02 = x*z, a12 = y*z;
    float R[9];
    R[0]=1.f+s2*a00;   R[1]=-st*z+s2*a01; R[2]= st*y+s2*a02;
    R[3]= st*z+s2*a01; R[4]=1.f+s2*a11;   R[5]=-st*x+s2*a12;
    R[6]=-st*y+s2*a02; R[7]= st*x+s2*a12; R[8]=1.f+s2*a22;
    if (near) { R[0]=1;R[1]=0;R[2]=0;R[3]=0;R[4]=1;R[5]=0;R[6]=0;R[7]=0;R[8]=1; }
    const float g3 = th - st;
    const float u0 = l0*inv, u1 = l1*inv, u2 = l2*inv;
    float p0 = th*u0 + s2*(-z*u1+y*u2) + g3*(a00*u0+a01*u1+a02*u2);
    float p1 = th*u1 + s2*( z*u0-x*u2) + g3*(a01*u0+a11*u1+a12*u2);
    float p2 = th*u2 + s2*(-y*u0+x*u1) + g3*(a02*u0+a12*u1+a22*u2);
    if (near) { p0=l0; p1=l1; p2=l2; }
#pragma unroll
    for (int r = 0; r < 3; ++r)
#pragma unroll
        for (int cc = 0; cc < 3; ++cc)
            TR[r*3+cc] = R[r*3+0]*Mj[cc*4+0] + R[r*3+1]*Mj[cc*4+1] + R[r*3+2]*Mj[cc*4+2];
    const float mp0 = Mj[3], mp1 = Mj[7], mp2 = Mj[11];
    Tp[0] = p0 - (TR[0]*mp0 + TR[1]*mp1 + TR[2]*mp2);
    Tp[1] = p1 - (TR[3]*mp0 + TR[4]*mp1 + TR[5]*mp2);
    Tp[2] = p2 - (TR[6]*mp0 + TR[7]*mp1 + TR[8]*mp2);
}

// ---------- main: R10 base + dq staged coalesced + T software-pipeline.
//            Requires B % BLK == 0. ----------
__global__ void __launch_bounds__(BLK)
id_main(const float* __restrict__ q, const float* __restrict__ dq,
        const float* __restrict__ ddq, const float* __restrict__ gvec,
        const float* __restrict__ Ftip, const float* __restrict__ Alist,
        const float* __restrict__ Mlist, const float* __restrict__ Glist,
        float* __restrict__ out, int B)
{
    __shared__ float sQ[JN][BLK + 1];   // q rows; reused for sigma after consumption
    __shared__ float sDQ[JN][BLK + 1];  // dq rows
    __shared__ float sB[JN * 6][BLK];   // base-frame screw axes (write once)

    const int tid = threadIdx.x;
    const int b = blockIdx.x * BLK + tid;

    // one-time COALESCED staging of this block's q and dq slabs
    {
        const float* qBlk  = q  + (size_t)blockIdx.x * BLK * JN;
        const float* dqBlk = dq + (size_t)blockIdx.x * BLK * JN;
#pragma unroll
        for (int k = 0; k < JN; ++k) {
            const int m = k * BLK + tid;
            sQ[m % JN][m / JN]  = qBlk[m];
            sDQ[m % JN][m / JN] = dqBlk[m];
        }
    }
    __syncthreads();
    // after this barrier each thread touches only its own column -> no further syncs

    float Ft[6];
    __builtin_memcpy(Ft, Ftip + (size_t)b * 6, 6 * sizeof(float));

    const float g0 = gvec[0], g1 = gvec[1], g2 = gvec[2];
    float XR[9] = {1.f,0.f,0.f, 0.f,1.f,0.f, 0.f,0.f,1.f};
    float Xp[3] = {0.f, 0.f, 0.f};
    float bv[6] = {0.f,0.f,0.f,0.f,0.f,0.f};
    float ba[6] = {0.f, 0.f, 0.f, -g0, -g1, -g2};
    float U[6]  = {0.f,0.f,0.f,0.f,0.f,0.f};

    // ---- T pipeline: TR/Tp hold T_j at iteration j; built one iter ahead ----
    float TR[9], Tp[3];
    make_T(Alist, Mlist, sQ[0][tid], TR, Tp);

#pragma unroll 1
    for (int j = 0; j < JN; ++j) {
        const float dqj  = sDQ[j][tid];                // fast ds_read
        const float ddqj = ddq[(size_t)b * JN + j];    // consumed late; latency hides

        // ---- X_j = T_j @ X_{j-1}  (T ready from previous iteration) ----
        {
            float nR[9], np[3];
#pragma unroll
            for (int r = 0; r < 3; ++r)
#pragma unroll
                for (int cc = 0; cc < 3; ++cc)
                    nR[r*3+cc] = TR[r*3+0]*XR[0*3+cc] + TR[r*3+1]*XR[1*3+cc] + TR[r*3+2]*XR[2*3+cc];
            mat3_vec(TR, Xp, np);
#pragma unroll
            for (int e = 0; e < 9; ++e) XR[e] = nR[e];
            Xp[0] = np[0]+Tp[0]; Xp[1] = np[1]+Tp[1]; Xp[2] = np[2]+Tp[2];
        }

        // ---- B_j = Ad(X_j^{-1}) A_j ----
        const float* Am = Alist + j * 6;               // uniform -> s_load
        float Aj[6];
#pragma unroll
        for (int k = 0; k < 6; ++k) Aj[k] = Am[k];
        float Bv[6];
        {
            float ip[3], tw[3], tv[3], cr[3];
            mat3T_vec(XR, Xp, ip);
            ip[0]=-ip[0]; ip[1]=-ip[1]; ip[2]=-ip[2];
            mat3T_vec(XR, Aj, tw);
            mat3T_vec(XR, Aj+3, tv);
            cross3(ip, tw, cr);
            Bv[0]=tw[0]; Bv[1]=tw[1]; Bv[2]=tw[2];
            Bv[3]=cr[0]+tv[0]; Bv[4]=cr[1]+tv[1]; Bv[5]=cr[2]+tv[2];
        }

        // ---- sigma_j = B_j . U_{j-1} ----
        const float sg = Bv[0]*U[0]+Bv[1]*U[1]+Bv[2]*U[2]
                       + Bv[3]*U[3]+Bv[4]*U[4]+Bv[5]*U[5];

        // ---- build T_{j+1} now (independent of X_j) so it overlaps the tail ----
        if (j + 1 < JN) {
            float TRn[9], Tpn[3];
            make_T(Alist + (j+1)*6, Mlist + (j+1)*16, sQ[j+1][tid], TRn, Tpn);
#pragma unroll
            for (int e = 0; e < 9; ++e) TR[e] = TRn[e];
            Tp[0]=Tpn[0]; Tp[1]=Tpn[1]; Tp[2]=Tpn[2];
        }

        // ---- base-frame twist/accel ----
#pragma unroll
        for (int k = 0; k < 6; ++k) bv[k] += Bv[k]*dqj;
        {
            float t0[3], t1[3], t2[3];
            cross3(bv, Bv, t0); cross3(bv+3, Bv, t1); cross3(bv, Bv+3, t2);
            ba[0] += t0[0]*dqj + Bv[0]*ddqj;
            ba[1] += t0[1]*dqj + Bv[1]*ddqj;
            ba[2] += t0[2]*dqj + Bv[2]*ddqj;
            ba[3] += (t1[0]+t2[0])*dqj + Bv[3]*ddqj;
            ba[4] += (t1[1]+t2[1])*dqj + Bv[4]*ddqj;
            ba[5] += (t1[2]+t2[2])*dqj + Bv[5]*ddqj;
        }

        // ---- link-frame v,a ; W ; S ; U ----
        float vl[6], al[6];
        adj_apply(XR, Xp, bv, vl);
        adj_apply(XR, Xp, ba, al);
        const float* Gm = Glist + j * 36;              // uniform -> s_load
        float Gv[6], Ga[6];
#pragma unroll
        for (int r = 0; r < 6; ++r) {
            float sv = 0.f, sa = 0.f;
#pragma unroll
            for (int kk = 0; kk < 6; ++kk) { sv += Gm[r*6+kk]*vl[kk]; sa += Gm[r*6+kk]*al[kk]; }
            Gv[r] = sv; Ga[r] = sa;
        }
        float W[6];
        {
            float cw[3], cv[3], cb[3];
            cross3(vl, Gv, cw); cross3(vl+3, Gv+3, cv); cross3(vl, Gv+3, cb);
            W[0]=Ga[0]+cw[0]+cv[0]; W[1]=Ga[1]+cw[1]+cv[1]; W[2]=Ga[2]+cw[2]+cv[2];
            W[3]=Ga[3]+cb[0];       W[4]=Ga[4]+cb[1];       W[5]=Ga[5]+cb[2];
        }
        {
            float S[6];
            adjT_apply(XR, Xp, W, S);
#pragma unroll
            for (int k = 0; k < 6; ++k) U[k] += S[k];
        }

        // ---- stash: B_j -> sB ; sigma_j overwrites the consumed q row ----
#pragma unroll
        for (int k = 0; k < 6; ++k) sB[j*6+k][tid] = Bv[k];
        sQ[j][tid] = sg;
    }

    // ---- epilogue: X_9 = inv(M_9) X_8 ; Z = Ad(X_9)^T Ftip ; tau ----
    float E[6];
    {
        const float* M9 = Mlist + JN * 16;
        float R9[9], p9[3];
#pragma unroll
        for (int r = 0; r < 3; ++r)
#pragma unroll
            for (int cc = 0; cc < 3; ++cc)
                R9[r*3+cc] = M9[0*4+r]*XR[0*3+cc] + M9[1*4+r]*XR[1*3+cc] + M9[2*4+r]*XR[2*3+cc];
        float t[3] = {Xp[0]-M9[3], Xp[1]-M9[7], Xp[2]-M9[11]};
        p9[0] = M9[0]*t[0] + M9[4]*t[1] + M9[8]*t[2];
        p9[1] = M9[1]*t[0] + M9[5]*t[1] + M9[9]*t[2];
        p9[2] = M9[2]*t[0] + M9[6]*t[1] + M9[10]*t[2];
        float Z[6];
        adjT_apply(R9, p9, Ft, Z);
#pragma unroll
        for (int k = 0; k < 6; ++k) E[k] = U[k] + Z[k];
    }
#pragma unroll
    for (int i = 0; i < JN; ++i) {
        float d = -sQ[i][tid];      // sigma_i
#pragma unroll
        for (int k = 0; k < 6; ++k) d += sB[i*6+k][tid] * E[k];
        out[(size_t)b*JN + i] = d;
    }
}

// ---------- fallback: R5 kernel (any B) ----------
__global__ void __launch_bounds__(BLK)
id_kernel_fb(const float* __restrict__ q, const float* __restrict__ dq,
             const float* __restrict__ ddq, const float* __restrict__ gvec,
             const float* __restrict__ Ftip, const float* __restrict__ Alist,
             const float* __restrict__ Mlist, const float* __restrict__ Glist,
             float* __restrict__ out, int B)
{
    __shared__ float sB[JN * 6][BLK];
    __shared__ float sSig[JN][BLK];
    const int tid = threadIdx.x;
    const int b = blockIdx.x * BLK + tid;
    if (b >= B) return;
    float XR[9] = {1.f,0.f,0.f, 0.f,1.f,0.f, 0.f,0.f,1.f};
    float Xp[3] = {0.f, 0.f, 0.f};
    float bv[6] = {0.f,0.f,0.f,0.f,0.f,0.f};
    float ba[6] = {0.f, 0.f, 0.f, -gvec[0], -gvec[1], -gvec[2]};
    float U[6]  = {0.f,0.f,0.f,0.f,0.f,0.f};
#pragma unroll 1
    for (int j = 0; j < JN; ++j) {
        const float* Am = Alist + j * 6;
        const float* Gm = Glist + j * 36;
        const float* Mj = Mlist + j * 16;
        float Aj[6];
#pragma unroll
        for (int k = 0; k < 6; ++k) Aj[k] = Am[k];
        const float qj = q[b*JN+j], dqj = dq[b*JN+j], ddqj = ddq[b*JN+j];
        float TR[9], Tp[3];
        make_T(Aj, Mj, qj, TR, Tp);
        {
            float nR[9], np[3];
#pragma unroll
            for (int r = 0; r < 3; ++r)
#pragma unroll
                for (int cc = 0; cc < 3; ++cc)
                    nR[r*3+cc] = TR[r*3+0]*XR[0*3+cc] + TR[r*3+1]*XR[1*3+cc] + TR[r*3+2]*XR[2*3+cc];
            mat3_vec(TR, Xp, np);
#pragma unroll
            for (int e = 0; e < 9; ++e) XR[e] = nR[e];
            Xp[0] = np[0]+Tp[0]; Xp[1] = np[1]+Tp[1]; Xp[2] = np[2]+Tp[2];
        }
        float Bv[6];
        {
            float ip[3], tw[3], tvv[3], cr[3];
            mat3T_vec(XR, Xp, ip);
            ip[0]=-ip[0]; ip[1]=-ip[1]; ip[2]=-ip[2];
            mat3T_vec(XR, Aj, tw);
            mat3T_vec(XR, Aj+3, tvv);
            cross3(ip, tw, cr);
            Bv[0]=tw[0]; Bv[1]=tw[1]; Bv[2]=tw[2];
            Bv[3]=cr[0]+tvv[0]; Bv[4]=cr[1]+tvv[1]; Bv[5]=cr[2]+tvv[2];
        }
        float sg = Bv[0]*U[0]+Bv[1]*U[1]+Bv[2]*U[2]+Bv[3]*U[3]+Bv[4]*U[4]+Bv[5]*U[5];
#pragma unroll
        for (int k = 0; k < 6; ++k) bv[k] += Bv[k]*dqj;
        {
            float t0[3], t1[3], t2[3];
            cross3(bv, Bv, t0); cross3(bv+3, Bv, t1); cross3(bv, Bv+3, t2);
            ba[0] += t0[0]*dqj + Bv[0]*ddqj;
            ba[1] += t0[1]*dqj + Bv[1]*ddqj;
            ba[2] += t0[2]*dqj + Bv[2]*ddqj;
            ba[3] += (t1[0]+t2[0])*dqj + Bv[3]*ddqj;
            ba[4] += (t1[1]+t2[1])*dqj + Bv[4]*ddqj;
            ba[5] += (t1[2]+t2[2])*dqj + Bv[5]*ddqj;
        }
        float vl[6], al[6];
        adj_apply(XR, Xp, bv, vl);
        adj_apply(XR, Xp, ba, al);
        float Gv[6], Ga[6];
#pragma unroll
        for (int r = 0; r < 6; ++r) {
            float sv = 0.f, sa = 0.f;
#pragma unroll
            for (int kk = 0; kk < 6; ++kk) { sv += Gm[r*6+kk]*vl[kk]; sa += Gm[r*6+kk]*al[kk]; }
            Gv[r] = sv; Ga[r] = sa;
        }
        float W[6];
        {
            float cw[3], cv[3], cb[3];
            cross3(vl, Gv, cw); cross3(vl+3, Gv+3, cv); cross3(vl, Gv+3, cb);
            W[0]=Ga[0]+cw[0]+cv[0]; W[1]=Ga[1]+cw[1]+cv[1]; W[2]=Ga[2]+cw[2]+cv[2];
            W[3]=Ga[3]+cb[0];       W[4]=Ga[4]+cb[1];       W[5]=Ga[5]+cb[2];
        }
        {
            float S[6];
            adjT_apply(XR, Xp, W, S);
#pragma unroll
            for (int k = 0; k < 6; ++k) U[k] += S[k];
        }
#pragma unroll
        for (int k = 0; k < 6; ++k) sB[j*6+k][tid] = Bv[k];
        sSig[j][tid] = sg;
    }
    float E[6];
    {
        const float* M9 = Mlist + JN * 16;
        float R9[9], p9[3];
#pragma unroll
        for (int r = 0; r < 3; ++r)
#pragma unroll
            for (int cc = 0; cc < 3; ++cc)
                R9[r*3+cc] = M9[0*4+r]*XR[0*3+cc] + M9[1*4+r]*XR[1*3+cc] + M9[2*4+r]*XR[2*3+cc];
        float t[3] = {Xp[0]-M9[3], Xp[1]-M9[7], Xp[2]-M9[11]};
        p9[0] = M9[0]*t[0] + M9[4]*t[1] + M9[8]*t[2];
        p9[1] = M9[1]*t[0] + M9[5]*t[1] + M9[9]*t[2];
        p9[2] = M9[2]*t[0] + M9[6]*t[1] + M9[10]*t[2];
        float Ftl[6];
#pragma unroll
        for (int k = 0; k < 6; ++k) Ftl[k] = Ftip[b*6+k];
        float Z[6];
        adjT_apply(R9, p9, Ftl, Z);
#pragma unroll
        for (int k = 0; k < 6; ++k) E[k] = U[k] + Z[k];
    }
#pragma unroll
    for (int i = 0; i < JN; ++i) {
        float d = -sSig[i][tid];
#pragma unroll
        for (int k = 0; k < 6; ++k) d += sB[i*6+k][tid] * E[k];
        out[b*JN+i] = d;
    }
}

extern "C" void kernel_launch(void* const* d_in, const int* in_sizes, int n_in,
                              void* d_out, int out_size, void* d_ws, size_t ws_size,
                              hipStream_t stream) {
    const float* q     = (const float*)d_in[0];
    const float* dq    = (const float*)d_in[1];
    const float* ddq   = (const float*)d_in[2];
    const float* g     = (const float*)d_in[3];
    const float* Ftip  = (const float*)d_in[4];
    const float* Alist = (const float*)d_in[5];
    const float* Mlist = (const float*)d_in[6];
    const float* Glist = (const float*)d_in[7];
    float* out = (float*)d_out;
    const int B = in_sizes[0] / JN;

    if ((B % BLK) == 0) {
        const int grid = B / BLK;
        hipLaunchKernelGGL(id_main, dim3(grid), dim3(BLK), 0, stream,
                           q, dq, ddq, g, Ftip, Alist, Mlist, Glist, out, B);
    } else {
        const int grid = (B + BLK - 1) / BLK;
        hipLaunchKernelGGL(id_kernel_fb, dim3(grid), dim3(BLK), 0, stream,
                           q, dq, ddq, g, Ftip, Alist, Mlist, Glist, out, B);
    }
}

// Round 13
// 26.805 us; speedup vs baseline: 1.4277x; 1.0768x over previous
//
#include <hip/hip_runtime.h>
#include <math.h>

#define JN 9
#define BLK 128

__device__ __forceinline__ void mat3_vec(const float* R, const float* x, float* y) {
    y[0] = R[0]*x[0] + R[1]*x[1] + R[2]*x[2];
    y[1] = R[3]*x[0] + R[4]*x[1] + R[5]*x[2];
    y[2] = R[6]*x[0] + R[7]*x[1] + R[8]*x[2];
}

// y = R^T x
__device__ __forceinline__ void mat3T_vec(const float* R, const float* x, float* y) {
    y[0] = R[0]*x[0] + R[3]*x[1] + R[6]*x[2];
    y[1] = R[1]*x[0] + R[4]*x[1] + R[7]*x[2];
    y[2] = R[2]*x[0] + R[5]*x[1] + R[8]*x[2];
}

__device__ __forceinline__ void cross3(const float* a, const float* b, float* o) {
    o[0] = a[1]*b[2] - a[2]*b[1];
    o[1] = a[2]*b[0] - a[0]*b[2];
    o[2] = a[0]*b[1] - a[1]*b[0];
}

// y = Adjoint(T) x for T=(R,p):  y_w = R x_w ;  y_v = p x (R x_w) + R x_v
__device__ __forceinline__ void adj_apply(const float* R, const float* p,
                                          const float* x, float* y) {
    float t[3], cr[3], rv[3];
    mat3_vec(R, x, t);
    cross3(p, t, cr);
    mat3_vec(R, x + 3, rv);
    y[0] = t[0]; y[1] = t[1]; y[2] = t[2];
    y[3] = cr[0] + rv[0]; y[4] = cr[1] + rv[1]; y[5] = cr[2] + rv[2];
}

// y = Adjoint(T)^T x for T=(R,p): y_w = R^T (x_w - p x x_v) ; y_v = R^T x_v
__device__ __forceinline__ void adjT_apply(const float* R, const float* p,
                                           const float* x, float* y) {
    float cr[3], t[3];
    cross3(p, x + 3, cr);
    t[0] = x[0] - cr[0]; t[1] = x[1] - cr[1]; t[2] = x[2] - cr[2];
    mat3T_vec(R, t, y);
    mat3T_vec(R, x + 3, y + 3);
}

// Best-measured variant (R5 bench: 26.88 us). Rolled loop, uniform constants
// via scalar loads, per-thread write-once B/sigma stash in LDS, O(N) prefix
// formulation: tau_i = B_i . (U_8 + Z) - sigma_i.
__global__ void __launch_bounds__(BLK)
id_kernel(const float* __restrict__ q, const float* __restrict__ dq,
          const float* __restrict__ ddq, const float* __restrict__ gvec,
          const float* __restrict__ Ftip, const float* __restrict__ Alist,
          const float* __restrict__ Mlist, const float* __restrict__ Glist,
          float* __restrict__ out, int B)
{
    __shared__ float sB[JN * 6][BLK];   // base-frame screw axes B_i (write once)
    __shared__ float sSig[JN][BLK];     // sigma_i = B_i . U_{i-1}

    const int tid = threadIdx.x;
    const int b = blockIdx.x * BLK + tid;
    if (b >= B) return;

    // cumulative X_j = T_j ... T_0 ; base-frame twist/accel ; prefix sum U
    float XR[9] = {1.f,0.f,0.f, 0.f,1.f,0.f, 0.f,0.f,1.f};
    float Xp[3] = {0.f, 0.f, 0.f};
    float bv[6] = {0.f, 0.f, 0.f, 0.f, 0.f, 0.f};
    float ba[6] = {0.f, 0.f, 0.f, -gvec[0], -gvec[1], -gvec[2]};
    float U[6]  = {0.f, 0.f, 0.f, 0.f, 0.f, 0.f};

#pragma unroll 1
    for (int j = 0; j < JN; ++j) {
        // ---- uniform constants (scalar loads: address depends only on j) ----
        const float* __restrict__ Am = Alist + j * 6;
        const float* __restrict__ Gm = Glist + j * 36;
        const float* __restrict__ Mj = Mlist + j * 16;
        float Aj[6];
#pragma unroll
        for (int k = 0; k < 6; ++k) Aj[k] = Am[k];

        const float qj   = q[b * JN + j];
        const float dqj  = dq[b * JN + j];
        const float ddqj = ddq[b * JN + j];

        // ---- matrix_exp6(-Aj * qj) ----
        const float w0 = -Aj[0] * qj, w1 = -Aj[1] * qj, w2 = -Aj[2] * qj;
        const float l0 = -Aj[3] * qj, l1 = -Aj[4] * qj, l2 = -Aj[5] * qj;
        const float th = sqrtf(w0*w0 + w1*w1 + w2*w2);
        const bool near = th < 1e-6f;
        const float safe = near ? 1.f : th;
        const float inv = __builtin_amdgcn_rcpf(safe);
        const float x = w0 * inv, y = w1 * inv, z = w2 * inv;
        const float st = __sinf(th), ct = __cosf(th);
        const float s2 = 1.f - ct;
        const float a00 = -(z*z + y*y), a11 = -(z*z + x*x), a22 = -(y*y + x*x);
        const float a01 = x*y, a02 = x*z, a12 = y*z;
        float R[9];
        R[0] = 1.f + s2*a00;     R[1] = -st*z + s2*a01;  R[2] =  st*y + s2*a02;
        R[3] =  st*z + s2*a01;   R[4] = 1.f + s2*a11;    R[5] = -st*x + s2*a12;
        R[6] = -st*y + s2*a02;   R[7] =  st*x + s2*a12;  R[8] = 1.f + s2*a22;
        if (near) {
            R[0]=1.f; R[1]=0.f; R[2]=0.f;
            R[3]=0.f; R[4]=1.f; R[5]=0.f;
            R[6]=0.f; R[7]=0.f; R[8]=1.f;
        }
        const float g3 = th - st;
        const float u0 = l0 * inv, u1 = l1 * inv, u2 = l2 * inv;
        float p0 = th*u0 + s2*(-z*u1 + y*u2) + g3*(a00*u0 + a01*u1 + a02*u2);
        float p1 = th*u1 + s2*( z*u0 - x*u2) + g3*(a01*u0 + a11*u1 + a12*u2);
        float p2 = th*u2 + s2*(-y*u0 + x*u1) + g3*(a02*u0 + a12*u1 + a22*u2);
        if (near) { p0 = l0; p1 = l1; p2 = l2; }

        // ---- T = exp6(-A q) @ inv(M_j):  TR = R @ MrT ; Tp = p - TR @ Mp ----
        float TR[9], Tp[3];
        {
#pragma unroll
            for (int r = 0; r < 3; ++r) {
#pragma unroll
                for (int cc = 0; cc < 3; ++cc) {
                    TR[r*3+cc] = R[r*3+0]*Mj[cc*4+0] + R[r*3+1]*Mj[cc*4+1] + R[r*3+2]*Mj[cc*4+2];
                }
            }
            const float mp0 = Mj[3], mp1 = Mj[7], mp2 = Mj[11];
            Tp[0] = p0 - (TR[0]*mp0 + TR[1]*mp1 + TR[2]*mp2);
            Tp[1] = p1 - (TR[3]*mp0 + TR[4]*mp1 + TR[5]*mp2);
            Tp[2] = p2 - (TR[6]*mp0 + TR[7]*mp1 + TR[8]*mp2);
        }

        // ---- X_j = T_j @ X_{j-1} ----
        {
            float nR[9], np[3];
#pragma unroll
            for (int r = 0; r < 3; ++r) {
#pragma unroll
                for (int cc = 0; cc < 3; ++cc) {
                    nR[r*3+cc] = TR[r*3+0]*XR[0*3+cc] + TR[r*3+1]*XR[1*3+cc] + TR[r*3+2]*XR[2*3+cc];
                }
            }
            mat3_vec(TR, Xp, np);
#pragma unroll
            for (int r = 0; r < 9; ++r) XR[r] = nR[r];
            Xp[0] = np[0] + Tp[0]; Xp[1] = np[1] + Tp[1]; Xp[2] = np[2] + Tp[2];
        }

        // ---- B_j = Ad(X_j^{-1}) A_j ;  X^{-1} = (XR^T, -XR^T Xp) ----
        float Bv[6];
        {
            float ip[3];
            mat3T_vec(XR, Xp, ip);
            ip[0] = -ip[0]; ip[1] = -ip[1]; ip[2] = -ip[2];
            float tw[3], tv[3], cr[3];
            mat3T_vec(XR, Aj, tw);
            mat3T_vec(XR, Aj + 3, tv);
            cross3(ip, tw, cr);
            Bv[0] = tw[0]; Bv[1] = tw[1]; Bv[2] = tw[2];
            Bv[3] = cr[0] + tv[0]; Bv[4] = cr[1] + tv[1]; Bv[5] = cr[2] + tv[2];
        }

        // ---- sigma_j = B_j . U_{j-1} (before U update) ----
        float sig = Bv[0]*U[0] + Bv[1]*U[1] + Bv[2]*U[2]
                  + Bv[3]*U[3] + Bv[4]*U[4] + Bv[5]*U[5];

        // ---- base-frame twist/accel updates ----
#pragma unroll
        for (int k = 0; k < 6; ++k) bv[k] += Bv[k] * dqj;
        {
            float t0[3], t1[3], t2[3];
            cross3(bv, Bv, t0);        // w(bv) x B_w
            cross3(bv + 3, Bv, t1);    // v(bv) x B_w
            cross3(bv, Bv + 3, t2);    // w(bv) x B_v
            ba[0] += t0[0]*dqj + Bv[0]*ddqj;
            ba[1] += t0[1]*dqj + Bv[1]*ddqj;
            ba[2] += t0[2]*dqj + Bv[2]*ddqj;
            ba[3] += (t1[0]+t2[0])*dqj + Bv[3]*ddqj;
            ba[4] += (t1[1]+t2[1])*dqj + Bv[4]*ddqj;
            ba[5] += (t1[2]+t2[2])*dqj + Bv[5]*ddqj;
        }

        // ---- link-frame v, a ----
        float vl[6], al[6];
        adj_apply(XR, Xp, bv, vl);
        adj_apply(XR, Xp, ba, al);

        // ---- W_j = G al - ad(vl)^T (G vl) ----
        float Gv[6], Ga[6];
#pragma unroll
        for (int r = 0; r < 6; ++r) {
            float sv = 0.f, sa = 0.f;
#pragma unroll
            for (int kk = 0; kk < 6; ++kk) {
                sv += Gm[r*6+kk] * vl[kk];
                sa += Gm[r*6+kk] * al[kk];
            }
            Gv[r] = sv; Ga[r] = sa;
        }
        float W[6];
        {
            float cw[3], cv[3], cb[3];
            cross3(vl, Gv, cw);          // w x (Gv)_w
            cross3(vl + 3, Gv + 3, cv);  // vv x (Gv)_v
            cross3(vl, Gv + 3, cb);      // w x (Gv)_v
            W[0] = Ga[0]+cw[0]+cv[0]; W[1] = Ga[1]+cw[1]+cv[1]; W[2] = Ga[2]+cw[2]+cv[2];
            W[3] = Ga[3]+cb[0];       W[4] = Ga[4]+cb[1];       W[5] = Ga[5]+cb[2];
        }

        // ---- S_j = Ad(X_j)^T W_j ; U += S_j ----
        {
            float S[6];
            adjT_apply(XR, Xp, W, S);
#pragma unroll
            for (int k = 0; k < 6; ++k) U[k] += S[k];
        }

        // ---- stash B_j, sigma_j (write-once, read in epilogue) ----
#pragma unroll
        for (int k = 0; k < 6; ++k) sB[j * 6 + k][tid] = Bv[k];
        sSig[j][tid] = sig;
    }

    // ---- X_9 = inv(M_9) @ X_8 ; Z = Ad(X_9)^T Ftip ; E = U + Z ----
    float E[6];
    {
        const float* __restrict__ M9 = Mlist + JN * 16;
        // R9 = Mr9^T @ XR ; p9 = Mr9^T (Xp - Mp9)
        float R9[9], p9[3];
#pragma unroll
        for (int r = 0; r < 3; ++r) {
#pragma unroll
            for (int cc = 0; cc < 3; ++cc) {
                R9[r*3+cc] = M9[0*4+r]*XR[0*3+cc] + M9[1*4+r]*XR[1*3+cc] + M9[2*4+r]*XR[2*3+cc];
            }
        }
        float t[3] = { Xp[0] - M9[3], Xp[1] - M9[7], Xp[2] - M9[11] };
        p9[0] = M9[0*4+0]*t[0] + M9[1*4+0]*t[1] + M9[2*4+0]*t[2];
        p9[1] = M9[0*4+1]*t[0] + M9[1*4+1]*t[1] + M9[2*4+1]*t[2];
        p9[2] = M9[0*4+2]*t[0] + M9[1*4+2]*t[1] + M9[2*4+2]*t[2];
        float Ft[6];
#pragma unroll
        for (int k = 0; k < 6; ++k) Ft[k] = Ftip[b * 6 + k];
        float Z[6];
        adjT_apply(R9, p9, Ft, Z);
#pragma unroll
        for (int k = 0; k < 6; ++k) E[k] = U[k] + Z[k];
    }

    // ---- tau_i = B_i . E - sigma_i ----
#pragma unroll
    for (int i = 0; i < JN; ++i) {
        float d = -sSig[i][tid];
#pragma unroll
        for (int k = 0; k < 6; ++k) d += sB[i * 6 + k][tid] * E[k];
        out[b * JN + i] = d;
    }
}

extern "C" void kernel_launch(void* const* d_in, const int* in_sizes, int n_in,
                              void* d_out, int out_size, void* d_ws, size_t ws_size,
                              hipStream_t stream) {
    const float* q     = (const float*)d_in[0];
    const float* dq    = (const float*)d_in[1];
    const float* ddq   = (const float*)d_in[2];
    const float* g     = (const float*)d_in[3];
    const float* Ftip  = (const float*)d_in[4];
    const float* Alist = (const float*)d_in[5];
    const float* Mlist = (const float*)d_in[6];
    const float* Glist = (const float*)d_in[7];
    float* out = (float*)d_out;

    const int B = in_sizes[0] / JN;
    const int grid = (B + BLK - 1) / BLK;
    hipLaunchKernelGGL(id_kernel, dim3(grid), dim3(BLK), 0, stream,
                       q, dq, ddq, g, Ftip, Alist, Mlist, Glist, out, B);
}